// Round 9
// baseline (19.091 us; speedup 1.0000x reference)
//
#include <hip/hip_runtime.h>

// P=40000, DEG=16, CI=CO=16.
// Single kernel, no workspace. Contraction order:
//   h[p][d][i] = sum_n r[p,n,d] * feat[nbr(p,n)][i]     (edge loop: feat only, L2-resident)
//   out[p][o]  = sum_d sum_i W[d][o][i] * h[p][d][i]
// Block = 256 = 16 points x 16 lanes (li = i in phase A, o in phase B).
// DS-pipe-minimal: the ONLY LDS traffic is the h transpose (3 write_b32 +
// 12 read_b128 per lane) + one barrier. W / radii / bs all come from global
// (L1-resident broadcasts / coalesced per-lane rows) on the idle VMEM pipe.

__global__ __launch_bounds__(256) void k_conv(const float* __restrict__ feat,
                                              const float* __restrict__ radii,
                                              const float* __restrict__ W,
                                              const int* __restrict__ bs,
                                              float* __restrict__ out,
                                              int P) {
    __shared__ __align__(16) float s_h[16][48];   // [lp][d*16+i]

    const int tid = threadIdx.x;
    const int pbase = blockIdx.x * 16;
    const int lp = tid >> 4;          // local point 0..15
    const int li = tid & 15;          // input channel i / output channel o

    const int p = pbase + lp;
    const bool alive = (p < P);
    const int psafe = alive ? p : 0;  // clamp: loads valid, result discarded

    // radii row: 12 same-address float4 global loads per 16-lane group
    // (row is 192 B at radii + p*192, 16B-aligned).
    float rr[48];
    {
        const float4* r4 = reinterpret_cast<const float4*>(radii + (size_t)psafe * 48);
#pragma unroll
        for (int j = 0; j < 12; ++j) {
            const float4 v = r4[j];
            rr[j*4+0] = v.x; rr[j*4+1] = v.y; rr[j*4+2] = v.z; rr[j*4+3] = v.w;
        }
    }
    // neighbor row: 16 same-address scalar loads (addresses loop-invariant,
    // issued in parallel; bs row = 17 ints, +1 col offset -> 4B-aligned only).
    int nb[16];
    {
        const int* bp = bs + (size_t)psafe * 17 + 1;
#pragma unroll
        for (int n = 0; n < 16; ++n) nb[n] = bp[n];
    }

    // --- Phase A: h[d] for i = li ---
    float h0 = 0.f, h1 = 0.f, h2 = 0.f;
#pragma unroll
    for (int n = 0; n < 16; ++n) {
        const float fv = feat[((size_t)nb[n] << 4) + li];  // 64B coalesced per group
        h0 += rr[n*3+0] * fv;
        h1 += rr[n*3+1] * fv;
        h2 += rr[n*3+2] * fv;
    }
    s_h[lp][li]      = h0;
    s_h[lp][16 + li] = h1;
    s_h[lp][32 + li] = h2;
    __syncthreads();

    // --- Phase B: out[p][o=li] = sum_d sum_i W[d][li][i] * h[lp][d*16+i] ---
    // W rows for channel li read directly from global: W flat [3][16][16],
    // float4 unit index = d*64 + li*4 + j. Per-lane 64B rows, L1-resident.
    float acc = 0.f;
    {
        const float4* Wv = reinterpret_cast<const float4*>(W);
        const float4* h4 = reinterpret_cast<const float4*>(&s_h[lp][0]);
#pragma unroll
        for (int d = 0; d < 3; ++d) {
#pragma unroll
            for (int j = 0; j < 4; ++j) {
                const float4 w = Wv[d * 64 + li * 4 + j];
                const float4 h = h4[d * 4 + j];
                acc += w.x * h.x + w.y * h.y + w.z * h.z + w.w * h.w;
            }
        }
    }
    if (alive) out[(size_t)p * 16 + li] = acc;
}

extern "C" void kernel_launch(void* const* d_in, const int* in_sizes, int n_in,
                              void* d_out, int out_size, void* d_ws, size_t ws_size,
                              hipStream_t stream) {
    const float* feat  = (const float*)d_in[0];   // [P,16] f32
    const float* radii = (const float*)d_in[1];   // [E,3]  f32
    const float* W     = (const float*)d_in[2];   // [3,16,16] f32
    const int*   bs    = (const int*)d_in[3];     // [P,17] i32
    float* out = (float*)d_out;                   // [P,16] f32

    const int P = in_sizes[0] / 16;
    const int grid = (P + 15) / 16;
    k_conv<<<grid, 256, 0, stream>>>(feat, radii, W, bs, out, P);
}

// Round 10
// 12.591 us; speedup vs baseline: 1.5163x; 1.5163x over previous
//
#include <hip/hip_runtime.h>

// P=40000, DEG=16, CI=CO=16.
// Single kernel, no workspace. Contraction order:
//   h[p][d][i] = sum_n r[p,n,d] * feat[nbr(p,n)][i]     (edge loop: feat only, L2-resident)
//   out[p][o]  = sum_d sum_i W[d][o][i] * h[p][d][i]
// Block = 256 = 16 points x 16 lanes. R7 structure (DS-bound, 12.31us), with the
// DS payload halved by f16/u16 packing:
//   - W in LDS as f16, k-order k=i*3+d, rows padded to 56 halves (112B, 16B-aligned,
//     2-way bank aliasing = free). Phase-B read: 6 ds_read_b128 (was 12).
//   - h transpose in f16: 3 ds_write_b16 (k=3*li adjacent) + 6 b128 reads (was 12).
//   - nbr packed u16: 2 b128 reads (was 4).
//   - radii stay f32 (12 b128 broadcast reads) -> phase-A math all-f32.
// Phase B accumulates via v_dot2_f32_f16 (packed f16 dot into f32 acc).

typedef _Float16 half2v __attribute__((ext_vector_type(2)));

static __device__ inline half2v bc_h2(unsigned int u) {
    union { unsigned int u; half2v h; } t; t.u = u; return t.h;
}

__global__ __launch_bounds__(256) void k_conv(const float* __restrict__ feat,
                                              const float* __restrict__ radii,
                                              const float* __restrict__ W,
                                              const int* __restrict__ bs,
                                              float* __restrict__ out,
                                              int P) {
    __shared__ __align__(16) _Float16       s_Wh[16][56]; // [o][k=i*3+d], pad 48->56
    __shared__ __align__(16) unsigned short s_nb[16][16]; // [lp][n] u16
    __shared__ __align__(16) float          s_r[16][48];  // [lp][n*3+d] f32
    __shared__ __align__(16) _Float16       s_h[16][56];  // [lp][k=i*3+d], pad 48->56

    const int tid = threadIdx.x;
    const int pbase = blockIdx.x * 16;
    const int lp = tid >> 4;          // local point 0..15
    const int li = tid & 15;          // i (phase A) / o (phase B)

    // stage W: f16, k = i*3+d ordering
    for (int t = tid; t < 768; t += 256) {
        const int d = t >> 8, o = (t >> 4) & 15, i = t & 15;
        s_Wh[o][i * 3 + d] = (_Float16)W[t];
    }
    // stage neighbor indices as u16
    {
        const int p = pbase + lp;
        const int v = (p < P) ? bs[(size_t)p * 17 + 1 + li] : 0;
        s_nb[lp][li] = (unsigned short)v;
    }
    // stage radii: 768 floats = 192 float4, coalesced
    if (tid < 192) {
        const size_t gi4  = (size_t)pbase * 12 + tid;
        const size_t lim4 = (size_t)P * 12;
        float4 v = {0.f, 0.f, 0.f, 0.f};
        if (gi4 < lim4) v = reinterpret_cast<const float4*>(radii)[gi4];
        reinterpret_cast<float4*>(&s_r[0][0])[tid] = v;
    }
    __syncthreads();

    const int p = pbase + lp;

    // neighbor row: 2x b128, unpack u16 -> int
    int nb[16];
    {
        const uint4* q = reinterpret_cast<const uint4*>(&s_nb[lp][0]);
        const uint4 a = q[0], b = q[1];
        nb[0]=a.x&0xffff;  nb[1]=a.x>>16;  nb[2]=a.y&0xffff;  nb[3]=a.y>>16;
        nb[4]=a.z&0xffff;  nb[5]=a.z>>16;  nb[6]=a.w&0xffff;  nb[7]=a.w>>16;
        nb[8]=b.x&0xffff;  nb[9]=b.x>>16;  nb[10]=b.y&0xffff; nb[11]=b.y>>16;
        nb[12]=b.z&0xffff; nb[13]=b.z>>16; nb[14]=b.w&0xffff; nb[15]=b.w>>16;
    }
    // radii row: 12x b128 broadcast
    float rr[48];
    {
        const float4* r4 = reinterpret_cast<const float4*>(&s_r[lp][0]);
#pragma unroll
        for (int j = 0; j < 12; ++j) {
            const float4 v = r4[j];
            rr[j*4+0] = v.x; rr[j*4+1] = v.y; rr[j*4+2] = v.z; rr[j*4+3] = v.w;
        }
    }

    // Phase A: h[d] for i = li (all f32)
    float h0 = 0.f, h1 = 0.f, h2 = 0.f;
#pragma unroll
    for (int n = 0; n < 16; ++n) {
        const float fv = feat[((size_t)nb[n] << 4) + li];  // 64B coalesced per group
        h0 += rr[n*3+0] * fv;
        h1 += rr[n*3+1] * fv;
        h2 += rr[n*3+2] * fv;
    }
    // h -> LDS f16 at k = 3*li .. 3*li+2 (adjacent)
    s_h[lp][3*li + 0] = (_Float16)h0;
    s_h[lp][3*li + 1] = (_Float16)h1;
    s_h[lp][3*li + 2] = (_Float16)h2;
    __syncthreads();

    // Phase B: out[p][o=li] = sum_k Wh[li][k] * h[lp][k], 6x b128 each, dot2 accum
    float acc = 0.f;
    {
        const uint4* w4 = reinterpret_cast<const uint4*>(&s_Wh[li][0]);
        const uint4* h4 = reinterpret_cast<const uint4*>(&s_h[lp][0]);
#pragma unroll
        for (int j = 0; j < 6; ++j) {
            const uint4 wq = w4[j];
            const uint4 hq = h4[j];
#if __has_builtin(__builtin_amdgcn_fdot2)
            acc = __builtin_amdgcn_fdot2(bc_h2(wq.x), bc_h2(hq.x), acc, false);
            acc = __builtin_amdgcn_fdot2(bc_h2(wq.y), bc_h2(hq.y), acc, false);
            acc = __builtin_amdgcn_fdot2(bc_h2(wq.z), bc_h2(hq.z), acc, false);
            acc = __builtin_amdgcn_fdot2(bc_h2(wq.w), bc_h2(hq.w), acc, false);
#else
            const half2v wx = bc_h2(wq.x), hx = bc_h2(hq.x);
            const half2v wy = bc_h2(wq.y), hy = bc_h2(hq.y);
            const half2v wz = bc_h2(wq.z), hz = bc_h2(hq.z);
            const half2v ww = bc_h2(wq.w), hw = bc_h2(hq.w);
            acc += (float)wx.x*(float)hx.x + (float)wx.y*(float)hx.y;
            acc += (float)wy.x*(float)hy.x + (float)wy.y*(float)hy.y;
            acc += (float)wz.x*(float)hz.x + (float)wz.y*(float)hz.y;
            acc += (float)ww.x*(float)hw.x + (float)ww.y*(float)hw.y;
#endif
        }
    }
    if (p < P) out[(size_t)p * 16 + li] = acc;
}

extern "C" void kernel_launch(void* const* d_in, const int* in_sizes, int n_in,
                              void* d_out, int out_size, void* d_ws, size_t ws_size,
                              hipStream_t stream) {
    const float* feat  = (const float*)d_in[0];   // [P,16] f32
    const float* radii = (const float*)d_in[1];   // [E,3]  f32
    const float* W     = (const float*)d_in[2];   // [3,16,16] f32
    const int*   bs    = (const int*)d_in[3];     // [P,17] i32
    float* out = (float*)d_out;                   // [P,16] f32

    const int P = in_sizes[0] / 16;
    const int grid = (P + 15) / 16;
    k_conv<<<grid, 256, 0, stream>>>(feat, radii, W, bs, out, P);
}

// Round 11
// 11.827 us; speedup vs baseline: 1.6143x; 1.0646x over previous
//
#include <hip/hip_runtime.h>

// P=40000, DEG=16, CI=CO=16.
// One wave (64 threads) per 16 points; grid = P/16 = 2500 blocks.
//   Phase A (VALU): lane l = (pt = l&15, iq = l>>4) computes
//       h[d][i=4*iq+j] = sum_n r[pt][n][d] * feat[nbr[pt][n]][4*iq+j]
//     feat gathered as one dwordx4 per neighbor (16 points covered per instr).
//   Phase B (MFMA): D[16pt][16o] = sum_d H_d(16x16) @ W_d^T(16x16)
//     = 3 chained v_mfma_f32_16x16x16f16. Phase-A layout IS the A-fragment
//     (row=l&15, k=4*(l>>4)+j); W loads form the B-fragment (col=l&15).
//     No h transpose, no LDS round-trip, no second barrier.
// LDS: radii rows padded to 52 floats, bs rows to 20 ints -> 2-way banks (free),
// 16B-aligned for b128. W/h as f16 frags (absmax margin proven in R10).

typedef _Float16 half4v  __attribute__((ext_vector_type(4)));
typedef float    floatx4 __attribute__((ext_vector_type(4)));

__global__ __launch_bounds__(64) void k_conv(const float* __restrict__ feat,
                                             const float* __restrict__ radii,
                                             const float* __restrict__ W,
                                             const int* __restrict__ bs,
                                             float* __restrict__ out,
                                             int P) {
    __shared__ __align__(16) float s_r[16][52];   // [pt][n*3+d], pad 48->52
    __shared__ __align__(16) int   s_nb[16][20];  // [pt][n],     pad 16->20

    const int l = threadIdx.x;        // 0..63
    const int pbase = blockIdx.x * 16;

    // ---- stage radii: 768 floats = 192 float4, coalesced; lane handles f4 idx l, l+64, l+128
    {
        const size_t lim4 = (size_t)P * 12;
#pragma unroll
        for (int c = 0; c < 3; ++c) {
            const int f4i = c * 64 + l;                   // 0..191
            const size_t gidx = (size_t)pbase * 12 + f4i;
            float4 v = make_float4(0.f, 0.f, 0.f, 0.f);
            if (gidx < lim4) v = reinterpret_cast<const float4*>(radii)[gidx];
            const int row  = f4i / 12;
            const int col4 = f4i - row * 12;
            *reinterpret_cast<float4*>(&s_r[row][col4 * 4]) = v;
        }
    }
    // ---- stage bs: lane l -> row l>>2, cols (l&3)*4..+3 (scalar loads, 4B-aligned source)
    {
        const int row = l >> 2;
        const int c0  = (l & 3) * 4;
        const int p   = pbase + row;
        int4 v = make_int4(0, 0, 0, 0);
        if (p < P) {
            const int* bp = bs + (size_t)p * 17 + 1 + c0;
            v.x = bp[0]; v.y = bp[1]; v.z = bp[2]; v.w = bp[3];
        }
        *reinterpret_cast<int4*>(&s_nb[row][c0]) = v;
    }
    __syncthreads();

    const int pt = l & 15;            // phase-A point row / phase-B output channel col
    const int iq = l >> 4;            // k-quad

    // ---- B-fragments from W (global, L1-hot): B_d[k=i][n=o], lane: o=l&15, i=4*iq+j
    half4v bw0, bw1, bw2;
    {
        const float4* Wv = reinterpret_cast<const float4*>(W);
        const float4 w0 = Wv[  0 + pt * 4 + iq];
        const float4 w1 = Wv[ 64 + pt * 4 + iq];
        const float4 w2 = Wv[128 + pt * 4 + iq];
        bw0[0]=(_Float16)w0.x; bw0[1]=(_Float16)w0.y; bw0[2]=(_Float16)w0.z; bw0[3]=(_Float16)w0.w;
        bw1[0]=(_Float16)w1.x; bw1[1]=(_Float16)w1.y; bw1[2]=(_Float16)w1.z; bw1[3]=(_Float16)w1.w;
        bw2[0]=(_Float16)w2.x; bw2[1]=(_Float16)w2.y; bw2[2]=(_Float16)w2.z; bw2[3]=(_Float16)w2.w;
    }

    // ---- neighbor row for point pt: 4x b128 (4-lane broadcast, 2-way banks)
    int nb[16];
    {
        const int4* nb4 = reinterpret_cast<const int4*>(&s_nb[pt][0]);
#pragma unroll
        for (int c = 0; c < 4; ++c) {
            const int4 v = nb4[c];
            nb[c*4+0] = v.x; nb[c*4+1] = v.y; nb[c*4+2] = v.z; nb[c*4+3] = v.w;
        }
    }

    // ---- Phase A: h[d][j] for i = 4*iq+j ----
    float a00=0.f,a01=0.f,a02=0.f,a03=0.f;   // d=0
    float a10=0.f,a11=0.f,a12=0.f,a13=0.f;   // d=1
    float a20=0.f,a21=0.f,a22=0.f,a23=0.f;   // d=2
    const float4* feat4 = reinterpret_cast<const float4*>(feat);
    const float4* rrow  = reinterpret_cast<const float4*>(&s_r[pt][0]);
#pragma unroll
    for (int c = 0; c < 4; ++c) {
        // flat r row: [n*3+d]; chunk c covers n = 4c..4c+3 (12 floats = 3 float4)
        const float4 r0 = rrow[c*3+0];   // {n0.d0, n0.d1, n0.d2, n1.d0}
        const float4 r1 = rrow[c*3+1];   // {n1.d1, n1.d2, n2.d0, n2.d1}
        const float4 r2 = rrow[c*3+2];   // {n2.d2, n3.d0, n3.d1, n3.d2}
        float4 f;
        f = feat4[(size_t)nb[c*4+0] * 4 + iq];
        a00+=r0.x*f.x; a01+=r0.x*f.y; a02+=r0.x*f.z; a03+=r0.x*f.w;
        a10+=r0.y*f.x; a11+=r0.y*f.y; a12+=r0.y*f.z; a13+=r0.y*f.w;
        a20+=r0.z*f.x; a21+=r0.z*f.y; a22+=r0.z*f.z; a23+=r0.z*f.w;
        f = feat4[(size_t)nb[c*4+1] * 4 + iq];
        a00+=r0.w*f.x; a01+=r0.w*f.y; a02+=r0.w*f.z; a03+=r0.w*f.w;
        a10+=r1.x*f.x; a11+=r1.x*f.y; a12+=r1.x*f.z; a13+=r1.x*f.w;
        a20+=r1.y*f.x; a21+=r1.y*f.y; a22+=r1.y*f.z; a23+=r1.y*f.w;
        f = feat4[(size_t)nb[c*4+2] * 4 + iq];
        a00+=r1.z*f.x; a01+=r1.z*f.y; a02+=r1.z*f.z; a03+=r1.z*f.w;
        a10+=r1.w*f.x; a11+=r1.w*f.y; a12+=r1.w*f.z; a13+=r1.w*f.w;
        a20+=r2.x*f.x; a21+=r2.x*f.y; a22+=r2.x*f.z; a23+=r2.x*f.w;
        f = feat4[(size_t)nb[c*4+3] * 4 + iq];
        a00+=r2.y*f.x; a01+=r2.y*f.y; a02+=r2.y*f.z; a03+=r2.y*f.w;
        a10+=r2.z*f.x; a11+=r2.z*f.y; a12+=r2.z*f.z; a13+=r2.z*f.w;
        a20+=r2.w*f.x; a21+=r2.w*f.y; a22+=r2.w*f.z; a23+=r2.w*f.w;
    }

    // ---- A-fragments (f16) ----
    half4v ah0, ah1, ah2;
    ah0[0]=(_Float16)a00; ah0[1]=(_Float16)a01; ah0[2]=(_Float16)a02; ah0[3]=(_Float16)a03;
    ah1[0]=(_Float16)a10; ah1[1]=(_Float16)a11; ah1[2]=(_Float16)a12; ah1[3]=(_Float16)a13;
    ah2[0]=(_Float16)a20; ah2[1]=(_Float16)a21; ah2[2]=(_Float16)a22; ah2[3]=(_Float16)a23;

    // ---- Phase B: 3 chained MFMAs ----
    floatx4 acc = {0.f, 0.f, 0.f, 0.f};
    acc = __builtin_amdgcn_mfma_f32_16x16x16f16(ah0, bw0, acc, 0, 0, 0);
    acc = __builtin_amdgcn_mfma_f32_16x16x16f16(ah1, bw1, acc, 0, 0, 0);
    acc = __builtin_amdgcn_mfma_f32_16x16x16f16(ah2, bw2, acc, 0, 0, 0);

    // ---- store: D col = l&15 (=o), row = 4*(l>>4)+j (= point) ----
#pragma unroll
    for (int j = 0; j < 4; ++j) {
        const int prow = pbase + 4 * iq + j;
        if (prow < P) out[(size_t)prow * 16 + pt] = acc[j];
    }
}

extern "C" void kernel_launch(void* const* d_in, const int* in_sizes, int n_in,
                              void* d_out, int out_size, void* d_ws, size_t ws_size,
                              hipStream_t stream) {
    const float* feat  = (const float*)d_in[0];   // [P,16] f32
    const float* radii = (const float*)d_in[1];   // [E,3]  f32
    const float* W     = (const float*)d_in[2];   // [3,16,16] f32
    const int*   bs    = (const int*)d_in[3];     // [P,17] i32
    float* out = (float*)d_out;                   // [P,16] f32

    const int P = in_sizes[0] / 16;
    const int grid = (P + 15) / 16;
    k_conv<<<grid, 64, 0, stream>>>(feat, radii, W, bs, out, P);
}